// Round 3
// baseline (1168.510 us; speedup 1.0000x reference)
//
#include <hip/hip_runtime.h>
#include <hip/hip_bf16.h>
#include <math.h>

// ---------- types & helpers ----------
typedef __bf16 bf16x8 __attribute__((ext_vector_type(8)));
typedef float f32x4 __attribute__((ext_vector_type(4)));

#define DEV static __device__ __forceinline__

DEV unsigned short f2b(float f){
  unsigned int u = __float_as_uint(f);
  u += 0x7fffu + ((u>>16)&1u);
  return (unsigned short)(u>>16);
}
DEV float b2f(unsigned short h){ return __uint_as_float(((unsigned int)h)<<16); }
DEV unsigned int pck(float a, float b){
  return (unsigned int)f2b(a) | ((unsigned int)f2b(b)<<16);
}
DEV f32x4 mfma16(bf16x8 a, bf16x8 b, f32x4 c){
  return __builtin_amdgcn_mfma_f32_16x16x32_bf16(a,b,c,0,0,0);
}

// ---------- util: fp32 -> bf16 copy ----------
__global__ __launch_bounds__(256) void k_b16(
    const float* __restrict__ src, unsigned short* __restrict__ dst, int n){
  int i = blockIdx.x*256 + threadIdx.x;
  if (i < n) dst[i] = f2b(src[i]);
}

// ---------- I0: slots init ----------
__global__ __launch_bounds__(256) void k_slots_init(
    const float* __restrict__ noise, const float* __restrict__ mu,
    const float* __restrict__ ls, float* __restrict__ sf,
    unsigned short* __restrict__ sb){
  int i = blockIdx.x*256 + threadIdx.x;   // 131072 total
  int d = i & 255;
  float val = mu[d] + expf(ls[d]) * noise[i];
  sf[i] = val; sb[i] = f2b(val);
}

// ---------- P1: WcT[c][d] = sum_e Wq[e][d]*Wk[e][c] (bf16); bc[c]=sum_e bq[e]Wk[e][c];
//             wqbk[d]=sum_e Wq[e][d]*bk[e]; cbk=sum bq*bk ----------
__global__ __launch_bounds__(256) void k_pre1(
    const float* __restrict__ Wq, const float* __restrict__ Wk,
    const float* __restrict__ bq, const float* __restrict__ bk,
    unsigned short* __restrict__ WcT, float* __restrict__ bc,
    float* __restrict__ wqbk, float* __restrict__ cbk){
  int c = blockIdx.x, d = threadIdx.x;
  float acc = 0.f;
  for (int e=0;e<256;e++)
    acc += Wq[e*256+d] * Wk[e*256+c];
  WcT[c*256+d] = f2b(acc);
  __shared__ float red[256];
  red[d] = bq[d] * Wk[d*256+c];
  __syncthreads();
  for (int s2=128;s2>0;s2>>=1){ if (d<s2) red[d]+=red[d+s2]; __syncthreads(); }
  if (d==0) bc[c] = red[0];
  if (blockIdx.x==0){
    float a2=0.f;
    for (int e=0;e<256;e++) a2 += Wq[e*256+d]*bk[e];
    wqbk[d] = a2;
    __syncthreads();
    red[d] = bq[d]*bk[d];
    __syncthreads();
    for (int s2=128;s2>0;s2>>=1){ if (d<s2) red[d]+=red[d+s2]; __syncthreads(); }
    if (d==0) cbk[0] = red[0];
  }
}

// ---------- P2: WvihT[j][c] = sum_d W_ih[j][d]*Wv[d][c] (bf16);
//              bvih[j]=sum_d bv[d]W_ih[j][d]+b_ih[j] ----------
__global__ __launch_bounds__(256) void k_pre2(
    const float* __restrict__ W_ih, const float* __restrict__ Wv,
    const float* __restrict__ bv, const float* __restrict__ b_ih,
    unsigned short* __restrict__ WvihT, float* __restrict__ bvih){
  int j = blockIdx.x, c = threadIdx.x;
  float acc=0.f;
  for (int d=0; d<256; d++)
    acc += W_ih[j*256+d] * Wv[d*256+c];
  WvihT[j*256+c] = f2b(acc);
  __shared__ float red[256];
  red[c] = bv[c] * W_ih[j*256+c];
  __syncthreads();
  for (int s2=128;s2>0;s2>>=1){ if (c<s2) red[c]+=red[c+s2]; __syncthreads(); }
  if (c==0) bvih[j] = red[0] + b_ih[j];
}

// ---------- I1: sn=LN(slots); q' = sn@Wc + bc (bf16, padded to 16 slot rows);
//             dotbias[b][row] = sn.wqbk + cbk; zero attn_sum ----------
__global__ __launch_bounds__(256) void k_slot_q(
    const float* __restrict__ sf, const float* __restrict__ g,
    const float* __restrict__ be,
    const unsigned short* __restrict__ WcT, const float* __restrict__ bc,
    const float* __restrict__ wqbk, const float* __restrict__ cbk,
    unsigned short* __restrict__ qp, float* __restrict__ dotbias,
    float* __restrict__ attn_sum){
  __shared__ __align__(16) unsigned short sn[16][264];
  int b = blockIdx.x, t = threadIdx.x;
  if (t < 8) attn_sum[b*8+t] = 0.f;
  if (t < 8) dotbias[b*16+8+t] = 0.f;
  int r = t>>5, j = t&31;
  const float* pr = sf + (b*8+r)*256 + j*8;
  float v[8]; float s=0.f;
  #pragma unroll
  for (int i=0;i<8;i++){ v[i]=pr[i]; s+=v[i]; }
  s += __shfl_xor(s,1); s+=__shfl_xor(s,2); s+=__shfl_xor(s,4);
  s += __shfl_xor(s,8); s+=__shfl_xor(s,16);
  float m = s*(1.f/256.f);
  float vs=0.f;
  #pragma unroll
  for (int i=0;i<8;i++){ float d = v[i]-m; vs += d*d; }
  vs += __shfl_xor(vs,1); vs+=__shfl_xor(vs,2); vs+=__shfl_xor(vs,4);
  vs += __shfl_xor(vs,8); vs+=__shfl_xor(vs,16);
  float rstd = rsqrtf(vs*(1.f/256.f) + 1e-5f);
  float dp = 0.f;
  #pragma unroll
  for (int i=0;i<8;i++){
    int d = j*8+i;
    float snv = (v[i]-m)*rstd*g[d] + be[d];
    sn[r][d] = f2b(snv);
    dp += snv * wqbk[d];
  }
  dp += __shfl_xor(dp,1); dp+=__shfl_xor(dp,2); dp+=__shfl_xor(dp,4);
  dp += __shfl_xor(dp,8); dp+=__shfl_xor(dp,16);
  if (j==0) dotbias[b*16+r] = dp + cbk[0];
  // zero pad rows 8..15
  for (int rr=8; rr<16; ++rr){ sn[rr][t]=0; if (t<8) sn[rr][256+t]=0; }
  __syncthreads();
  int lane = t&63, wv = t>>6, l16 = lane&15, quad = lane>>4;
  #pragma unroll
  for (int nt=0; nt<4; ++nt){
    int col = (wv*4+nt)*16 + l16;
    f32x4 acc = {0.f,0.f,0.f,0.f};
    #pragma unroll
    for (int kk=0;kk<8;kk++){
      int kd = kk*32 + quad*8;
      bf16x8 a = *(const bf16x8*)&sn[l16][kd];
      bf16x8 bb = *(const bf16x8*)(WcT + col*256 + kd);
      acc = mfma16(a,bb,acc);
    }
    float bcv = bc[col];
    #pragma unroll
    for (int ri=0;ri<4;ri++){
      int rw = quad*4+ri;
      qp[(b*16+rw)*256 + col] = f2b(acc[ri] + bcv);
    }
  }
}

// ---------- I2 fused: per (b, 64-token chunk):
//   LN(x) tile -> LDS bf16; dots = q'.x^T*scale+bias via MFMA;
//   softmax over K (local per token); partial u[k][c] = sum_n attn*x;
//   attn row-sum atomics; optional attn output (last iter, fp32) ----------
__global__ __launch_bounds__(256) void k_iter(
    const float* __restrict__ in, const float* __restrict__ g,
    const float* __restrict__ be, const unsigned short* __restrict__ qp,
    const float* __restrict__ dotbias, float* __restrict__ attn_sum,
    float* __restrict__ upart, float* __restrict__ attn_out){
  __shared__ __align__(16) unsigned short xt[64][264];  // LN'd tile, bf16
  __shared__ __align__(16) float al[64][8];             // attn per token x slot
  __shared__ float bsum[8];
  int t = threadIdx.x;
  int b = blockIdx.x >> 6, nb = blockIdx.x & 63;
  if (t<8) bsum[t]=0.f;
  // --- stage 1: LayerNorm 64 rows of fp32 input into LDS (bf16) ---
  int rl = t>>3, j = t&7;   // 32 rows/pass, 8 threads/row, 32 elems/thread
  #pragma unroll
  for (int p=0;p<2;p++){
    int row = p*32 + rl;
    const float* pr = in + ((size_t)(b*4096 + nb*64 + row))*256 + j*32;
    float v[32]; float s=0.f;
    #pragma unroll
    for (int c=0;c<8;c++) *(float4*)(v+c*4) = *(const float4*)(pr + c*4);
    #pragma unroll
    for (int i=0;i<32;i++) s += v[i];
    s += __shfl_xor(s,1); s+=__shfl_xor(s,2); s+=__shfl_xor(s,4);
    float m = s*(1.f/256.f);
    float vs=0.f;
    #pragma unroll
    for (int i=0;i<32;i++){ float d=v[i]-m; vs+=d*d; }
    vs+=__shfl_xor(vs,1); vs+=__shfl_xor(vs,2); vs+=__shfl_xor(vs,4);
    float rstd = rsqrtf(vs*(1.f/256.f)+1e-5f);
    #pragma unroll
    for (int c=0;c<4;c++){
      float o[8];
      #pragma unroll
      for (int q=0;q<8;q++){
        int d = j*32 + c*8 + q;
        o[q] = (v[c*8+q]-m)*rstd*g[d] + be[d];
      }
      uint4 w4;
      w4.x=pck(o[0],o[1]); w4.y=pck(o[2],o[3]);
      w4.z=pck(o[4],o[5]); w4.w=pck(o[6],o[7]);
      *(uint4*)&xt[row][j*32 + c*8] = w4;
    }
  }
  __syncthreads();
  // --- stage 2: dots via MFMA + softmax over slots ---
  int lane=t&63, wv=t>>6, l16=lane&15, quad=lane>>4;
  f32x4 acc = {0.f,0.f,0.f,0.f};
  #pragma unroll
  for (int kk=0;kk<8;kk++){
    int kd = kk*32 + quad*8;
    bf16x8 a = *(const bf16x8*)(qp + ((size_t)(b*16+l16))*256 + kd);
    bf16x8 bb = *(const bf16x8*)&xt[wv*16 + l16][kd];
    acc = mfma16(a,bb,acc);
  }
  const float scale = 0.0625f;   // D^-0.5 = 1/16
  float val[4];
  #pragma unroll
  for (int ri=0;ri<4;ri++) val[ri] = (acc[ri] + dotbias[b*16 + quad*4 + ri]) * scale;
  float mx = fmaxf(fmaxf(val[0],val[1]), fmaxf(val[2],val[3]));
  mx = fmaxf(mx, __shfl_xor(mx,16));   // combine slots 0-3 with 4-7
  float e[4], s4=0.f;
  #pragma unroll
  for (int ri=0;ri<4;ri++){ e[ri] = expf(val[ri]-mx); s4 += e[ri]; }
  float s8 = s4 + __shfl_xor(s4,16);
  float inv = 1.f/s8;
  if (quad < 2){   // real slots 0..7 live in quads 0,1
    int nl = wv*16 + l16;
    #pragma unroll
    for (int ri=0;ri<4;ri++){
      float av = e[ri]*inv;
      int kr = quad*4+ri;
      al[nl][kr] = av;
      if (attn_out){
        int n = nb*64 + nl;
        attn_out[((size_t)(b*8+kr))*4096 + n] = av;
      }
      float ss = av;
      ss += __shfl_xor(ss,1); ss+=__shfl_xor(ss,2);
      ss += __shfl_xor(ss,4); ss+=__shfl_xor(ss,8);
      if (l16==0) atomicAdd(&bsum[kr], ss);
    }
  }
  __syncthreads();
  // --- stage 3: partial update u[k][c] = sum_n attn[k][n]*x[n][c] ---
  float acc8[8] = {0.f,0.f,0.f,0.f,0.f,0.f,0.f,0.f};
  int c = t;
  for (int n=0;n<64;++n){
    float xv = b2f(xt[n][c]);
    float4 a0 = *(const float4*)&al[n][0];
    float4 a1 = *(const float4*)&al[n][4];
    acc8[0]+=a0.x*xv; acc8[1]+=a0.y*xv; acc8[2]+=a0.z*xv; acc8[3]+=a0.w*xv;
    acc8[4]+=a1.x*xv; acc8[5]+=a1.y*xv; acc8[6]+=a1.z*xv; acc8[7]+=a1.w*xv;
  }
  float* o = upart + ((size_t)(nb*64+b)*8)*256 + c;
  #pragma unroll
  for (int k2=0;k2<8;k2++) o[(size_t)k2*256] = acc8[k2];
  if (t<8) atomicAdd(&attn_sum[b*8+t], bsum[t]);
}

// ---------- R3: reduce 64 partials, apply 1/(attn_sum+eps), store u' bf16 ----------
__global__ __launch_bounds__(256) void k_ured(
    const float* __restrict__ upart, const float* __restrict__ attn_sum,
    unsigned short* __restrict__ ub){
  int i = blockIdx.x*256 + threadIdx.x;  // 131072 = b*2048 + k*256 + c
  float s = 0.f;
  #pragma unroll
  for (int sp=0; sp<64; ++sp) s += upart[(size_t)sp*131072 + i];
  float inv = 1.f/(attn_sum[i>>8] + 1e-8f);
  ub[i] = f2b(s*inv);
}

// ---------- I4a: gi = u'@Wvih + bvih ; gh = slots@W_hh^T + b_hh ----------
__global__ __launch_bounds__(256) void k_gates(
    const unsigned short* __restrict__ ub, const unsigned short* __restrict__ sb,
    const unsigned short* __restrict__ WvihT, const float* __restrict__ bvih,
    const unsigned short* __restrict__ Whh_b, const float* __restrict__ b_hh,
    float* __restrict__ gi, float* __restrict__ gh){
  int t=threadIdx.x, lane=t&63, wv=t>>6, l16=lane&15, quad=lane>>4;
  int r0 = blockIdx.x*16;
  bf16x8 afi[8], afh[8];
  #pragma unroll
  for (int kk=0;kk<8;kk++){
    int kd = kk*32+quad*8;
    afi[kk] = *(const bf16x8*)(ub + (r0+l16)*256 + kd);
    afh[kk] = *(const bf16x8*)(sb + (r0+l16)*256 + kd);
  }
  for (int jt = wv*12; jt < wv*12+12; ++jt){
    int col = jt*16 + l16;
    f32x4 ai={0.f,0.f,0.f,0.f}, ah={0.f,0.f,0.f,0.f};
    #pragma unroll
    for (int kk=0;kk<8;kk++){
      int kd = kk*32+quad*8;
      ai = mfma16(afi[kk], *(const bf16x8*)(WvihT + col*256 + kd), ai);
      ah = mfma16(afh[kk], *(const bf16x8*)(Whh_b + col*256 + kd), ah);
    }
    float bi = bvih[col], bh = b_hh[col];
    #pragma unroll
    for (int ri=0;ri<4;ri++){
      int rw = quad*4+ri;
      gi[(size_t)(r0+rw)*768 + col] = ai[ri]+bi;
      gh[(size_t)(r0+rw)*768 + col] = ah[ri]+bh;
    }
  }
}

// ---------- I4b: GRU elementwise + LN(h) -> ff (bf16), h -> hbuf (fp32) ----------
__global__ __launch_bounds__(256) void k_gru(
    const float* __restrict__ gi, const float* __restrict__ gh,
    const float* __restrict__ sf_prev, const float* __restrict__ g,
    const float* __restrict__ be,
    float* __restrict__ hbuf, unsigned short* __restrict__ ff){
  int t=threadIdx.x;
  int rl = t>>3, j = t&7;
  int R = blockIdx.x*32 + rl;
  const float* pgi = gi + (size_t)R*768 + j*32;
  const float* pgh = gh + (size_t)R*768 + j*32;
  const float* ph  = sf_prev + (size_t)R*256 + j*32;
  float hv[32]; float s=0.f;
  #pragma unroll
  for (int i=0;i<32;i++){
    float ir = pgi[i], iz = pgi[256+i], inn = pgi[512+i];
    float hr = pgh[i], hz = pgh[256+i], hn = pgh[512+i];
    float rg = 1.f/(1.f+expf(-(ir+hr)));
    float z  = 1.f/(1.f+expf(-(iz+hz)));
    float nn = tanhf(inn + rg*hn);
    float h = (1.f-z)*nn + z*ph[i];
    hv[i]=h; s+=h;
  }
  s+=__shfl_xor(s,1); s+=__shfl_xor(s,2); s+=__shfl_xor(s,4);
  float m = s*(1.f/256.f);
  float vs=0.f;
  #pragma unroll
  for (int i=0;i<32;i++){ float d=hv[i]-m; vs+=d*d; }
  vs+=__shfl_xor(vs,1); vs+=__shfl_xor(vs,2); vs+=__shfl_xor(vs,4);
  float rstd = rsqrtf(vs*(1.f/256.f)+1e-5f);
  float* oh = hbuf + (size_t)R*256 + j*32;
  unsigned short* of = ff + (size_t)R*256 + j*32;
  #pragma unroll
  for (int i=0;i<32;i++) oh[i]=hv[i];
  #pragma unroll
  for (int c=0;c<4;c++){
    float o[8];
    #pragma unroll
    for (int q=0;q<8;q++){
      int d = j*32 + c*8 + q;
      o[q] = (hv[c*8+q]-m)*rstd*g[d] + be[d];
    }
    uint4 w4;
    w4.x = pck(o[0],o[1]); w4.y = pck(o[2],o[3]);
    w4.z = pck(o[4],o[5]); w4.w = pck(o[6],o[7]);
    *(uint4*)(of + c*8) = w4;
  }
}

// ---------- I5: s1 = relu(ff@W1^T + b1) (bf16) ----------
__global__ __launch_bounds__(256) void k_ffn1(
    const unsigned short* __restrict__ ff, const unsigned short* __restrict__ W1b,
    const float* __restrict__ b1, unsigned short* __restrict__ s1){
  int t=threadIdx.x, lane=t&63, wv=t>>6, l16=lane&15, quad=lane>>4;
  int r0 = blockIdx.x*16;
  bf16x8 af[8];
  #pragma unroll
  for (int kk=0;kk<8;kk++)
    af[kk] = *(const bf16x8*)(ff + (r0+l16)*256 + kk*32+quad*8);
  for (int jt=wv*8; jt<wv*8+8; ++jt){
    int col = jt*16+l16;
    f32x4 acc={0.f,0.f,0.f,0.f};
    #pragma unroll
    for (int kk=0;kk<8;kk++)
      acc = mfma16(af[kk], *(const bf16x8*)(W1b + col*256 + kk*32+quad*8), acc);
    float bb = b1[col];
    #pragma unroll
    for (int ri=0;ri<4;ri++){
      float v2 = acc[ri]+bb; v2 = v2>0.f? v2 : 0.f;
      s1[(size_t)(r0+quad*4+ri)*512+col] = f2b(v2);
    }
  }
}

// ---------- I6: slots = h + s1@W2^T + b2 (fp32 + bf16, optional fp32 final out) ----------
__global__ __launch_bounds__(256) void k_ffn2(
    const unsigned short* __restrict__ s1, const unsigned short* __restrict__ W2b,
    const float* __restrict__ b2v, const float* __restrict__ hbuf,
    float* __restrict__ sf, unsigned short* __restrict__ sb,
    float* __restrict__ out_slots){
  int t=threadIdx.x, lane=t&63, wv=t>>6, l16=lane&15, quad=lane>>4;
  int r0 = blockIdx.x*16;
  bf16x8 af[16];
  #pragma unroll
  for (int kk=0;kk<16;kk++)
    af[kk] = *(const bf16x8*)(s1 + (r0+l16)*512 + kk*32+quad*8);
  for (int jt=wv*4; jt<wv*4+4; ++jt){
    int col = jt*16+l16;
    f32x4 acc={0.f,0.f,0.f,0.f};
    #pragma unroll
    for (int kk=0;kk<16;kk++)
      acc = mfma16(af[kk], *(const bf16x8*)(W2b + col*512 + kk*32+quad*8), acc);
    float bb = b2v[col];
    #pragma unroll
    for (int ri=0;ri<4;ri++){
      int R = r0+quad*4+ri;
      float v2 = acc[ri] + bb + hbuf[(size_t)R*256+col];
      sf[(size_t)R*256+col] = v2;
      sb[(size_t)R*256+col] = f2b(v2);
      if (out_slots) out_slots[(size_t)R*256+col] = v2;
    }
  }
}

// ---------- launch ----------
extern "C" void kernel_launch(void* const* d_in, const int* in_sizes, int n_in,
                              void* d_out, int out_size, void* d_ws, size_t ws_size,
                              hipStream_t stream){
  const float* inputs  = (const float*)d_in[0];
  const float* noise   = (const float*)d_in[1];
  const float* slot_mu = (const float*)d_in[2];
  const float* slot_ls = (const float*)d_in[3];
  const float* Wq   = (const float*)d_in[4];
  const float* bq   = (const float*)d_in[5];
  const float* Wk   = (const float*)d_in[6];
  const float* bk   = (const float*)d_in[7];
  const float* Wv   = (const float*)d_in[8];
  const float* bv   = (const float*)d_in[9];
  const float* W_ih = (const float*)d_in[10];
  const float* b_ih = (const float*)d_in[11];
  const float* W_hh = (const float*)d_in[12];
  const float* b_hh = (const float*)d_in[13];
  const float* ln_in_g = (const float*)d_in[14];
  const float* ln_in_b = (const float*)d_in[15];
  const float* ln_s_g  = (const float*)d_in[16];
  const float* ln_s_b  = (const float*)d_in[17];
  const float* ln_ff_g = (const float*)d_in[18];
  const float* ln_ff_b = (const float*)d_in[19];
  const float* W1 = (const float*)d_in[20];
  const float* b1 = (const float*)d_in[21];
  const float* W2 = (const float*)d_in[22];
  const float* b2 = (const float*)d_in[23];

  char* w = (char*)d_ws;
  auto alloc = [&](size_t n)->char*{ char* p=w; w += (n+255)&~(size_t)255; return p; };
  float* upart         = (float*)alloc(33554432);           // [64,B,8,256] f32
  unsigned short* qp   = (unsigned short*)alloc(524288);    // [B,16,256] bf16
  unsigned short* ub   = (unsigned short*)alloc(262144);    // [512,256] bf16
  float* sf            = (float*)alloc(524288);             // slots f32
  unsigned short* sb   = (unsigned short*)alloc(262144);    // slots bf16
  float* gi            = (float*)alloc(1572864);            // [512,768] f32
  float* gh            = (float*)alloc(1572864);
  float* hbuf          = (float*)alloc(524288);             // [512,256] f32
  unsigned short* ff   = (unsigned short*)alloc(262144);
  unsigned short* s1   = (unsigned short*)alloc(524288);    // [512,512] bf16
  unsigned short* WcT  = (unsigned short*)alloc(131072);    // [256,256] bf16
  unsigned short* WvihT= (unsigned short*)alloc(393216);    // [768,256] bf16
  unsigned short* Whhb = (unsigned short*)alloc(393216);    // [768,256] bf16
  unsigned short* W1b  = (unsigned short*)alloc(262144);    // [512,256] bf16
  unsigned short* W2b  = (unsigned short*)alloc(262144);    // [256,512] bf16
  float* bc    = (float*)alloc(1024);
  float* wqbk  = (float*)alloc(1024);
  float* cbk   = (float*)alloc(256);
  float* bvih  = (float*)alloc(3072);
  float* dotb  = (float*)alloc(4096);
  float* asum  = (float*)alloc(2048);

  float* out_slots = (float*)d_out;
  float* out_attn  = out_slots + 131072;

  k_slots_init<<<dim3(512),dim3(256),0,stream>>>(noise, slot_mu, slot_ls, sf, sb);
  k_pre1<<<dim3(256),dim3(256),0,stream>>>(Wq, Wk, bq, bk, WcT, bc, wqbk, cbk);
  k_pre2<<<dim3(768),dim3(256),0,stream>>>(W_ih, Wv, bv, b_ih, WvihT, bvih);
  k_b16<<<dim3(768),dim3(256),0,stream>>>(W_hh, Whhb, 196608);
  k_b16<<<dim3(512),dim3(256),0,stream>>>(W1, W1b, 131072);
  k_b16<<<dim3(512),dim3(256),0,stream>>>(W2, W2b, 131072);

  for (int it=0; it<3; ++it){
    bool last = (it==2);
    k_slot_q<<<dim3(64),dim3(256),0,stream>>>(sf, ln_s_g, ln_s_b, WcT, bc, wqbk, cbk,
                                              qp, dotb, asum);
    k_iter<<<dim3(4096),dim3(256),0,stream>>>(inputs, ln_in_g, ln_in_b, qp, dotb, asum,
                                              upart, last ? out_attn : (float*)nullptr);
    k_ured<<<dim3(512),dim3(256),0,stream>>>(upart, asum, ub);
    k_gates<<<dim3(32),dim3(256),0,stream>>>(ub, sb, WvihT, bvih, Whhb, b_hh, gi, gh);
    k_gru<<<dim3(16),dim3(256),0,stream>>>(gi, gh, sf, ln_ff_g, ln_ff_b, hbuf, ff);
    k_ffn1<<<dim3(32),dim3(256),0,stream>>>(ff, W1b, b1, s1);
    k_ffn2<<<dim3(32),dim3(256),0,stream>>>(s1, W2b, b2, hbuf, sf, sb,
                                            last ? out_slots : (float*)nullptr);
  }
}

// Round 4
// 850.754 us; speedup vs baseline: 1.3735x; 1.3735x over previous
//
#include <hip/hip_runtime.h>
#include <hip/hip_bf16.h>
#include <math.h>

// ---------- types & helpers ----------
typedef __bf16 bf16x8 __attribute__((ext_vector_type(8)));
typedef float f32x4 __attribute__((ext_vector_type(4)));

#define DEV static __device__ __forceinline__

DEV unsigned short f2b(float f){
  unsigned int u = __float_as_uint(f);
  u += 0x7fffu + ((u>>16)&1u);
  return (unsigned short)(u>>16);
}
DEV float b2f(unsigned short h){ return __uint_as_float(((unsigned int)h)<<16); }
DEV unsigned int pck(float a, float b){
  return (unsigned int)f2b(a) | ((unsigned int)f2b(b)<<16);
}
DEV f32x4 mfma16(bf16x8 a, bf16x8 b, f32x4 c){
  return __builtin_amdgcn_mfma_f32_16x16x32_bf16(a,b,c,0,0,0);
}
DEV float sigm(float x){ return 1.f/(1.f+expf(-x)); }

// ---------- I0: slots init ----------
__global__ __launch_bounds__(256) void k_slots_init(
    const float* __restrict__ noise, const float* __restrict__ mu,
    const float* __restrict__ ls, float* __restrict__ sf,
    unsigned short* __restrict__ sb){
  int i = blockIdx.x*256 + threadIdx.x;   // 131072 total
  int d = i & 255;
  float val = mu[d] + expf(ls[d]) * noise[i];
  sf[i] = val; sb[i] = f2b(val);
}

// ---------- prep: bf16 copies of W_hh, W1, W2 ----------
__global__ __launch_bounds__(256) void k_prep_b16(
    const float* __restrict__ Whh, const float* __restrict__ W1,
    const float* __restrict__ W2,
    unsigned short* __restrict__ Whhb, unsigned short* __restrict__ W1b,
    unsigned short* __restrict__ W2b){
  int i = blockIdx.x*256 + threadIdx.x;
  if (i < 196608) Whhb[i] = f2b(Whh[i]);
  else if (i < 327680) W1b[i-196608] = f2b(W1[i-196608]);
  else if (i < 458752) W2b[i-327680] = f2b(W2[i-327680]);
}

// ---------- P1: WcT[c][d] = sum_e Wq[e][d]*Wk[e][c] (bf16); bc[c]=sum_e bq[e]Wk[e][c];
//             wqbk[d]=sum_e Wq[e][d]*bk[e]; cbk=sum bq*bk ----------
__global__ __launch_bounds__(256) void k_pre1(
    const float* __restrict__ Wq, const float* __restrict__ Wk,
    const float* __restrict__ bq, const float* __restrict__ bk,
    unsigned short* __restrict__ WcT, float* __restrict__ bc,
    float* __restrict__ wqbk, float* __restrict__ cbk){
  int c = blockIdx.x, d = threadIdx.x;
  float acc = 0.f;
  for (int e=0;e<256;e++)
    acc += Wq[e*256+d] * Wk[e*256+c];
  WcT[c*256+d] = f2b(acc);
  __shared__ float red[256];
  red[d] = bq[d] * Wk[d*256+c];
  __syncthreads();
  for (int s2=128;s2>0;s2>>=1){ if (d<s2) red[d]+=red[d+s2]; __syncthreads(); }
  if (d==0) bc[c] = red[0];
  if (blockIdx.x==0){
    float a2=0.f;
    for (int e=0;e<256;e++) a2 += Wq[e*256+d]*bk[e];
    wqbk[d] = a2;
    __syncthreads();
    red[d] = bq[d]*bk[d];
    __syncthreads();
    for (int s2=128;s2>0;s2>>=1){ if (d<s2) red[d]+=red[d+s2]; __syncthreads(); }
    if (d==0) cbk[0] = red[0];
  }
}

// ---------- P2: WvihT[j][c] = sum_d W_ih[j][d]*Wv[d][c] (bf16);
//              bvih[j]=sum_d bv[d]W_ih[j][d]+b_ih[j] ----------
__global__ __launch_bounds__(256) void k_pre2(
    const float* __restrict__ W_ih, const float* __restrict__ Wv,
    const float* __restrict__ bv, const float* __restrict__ b_ih,
    unsigned short* __restrict__ WvihT, float* __restrict__ bvih){
  int j = blockIdx.x, c = threadIdx.x;
  float acc=0.f;
  for (int d=0; d<256; d++)
    acc += W_ih[j*256+d] * Wv[d*256+c];
  WvihT[j*256+c] = f2b(acc);
  __shared__ float red[256];
  red[c] = bv[c] * W_ih[j*256+c];
  __syncthreads();
  for (int s2=128;s2>0;s2>>=1){ if (c<s2) red[c]+=red[c+s2]; __syncthreads(); }
  if (c==0) bvih[j] = red[0] + b_ih[j];
}

// ---------- I1 (first iteration only): sn=LN(slots); q' = sn@Wc + bc;
//             dotbias; zero attn_sum ----------
__global__ __launch_bounds__(256) void k_slot_q(
    const float* __restrict__ sf, const float* __restrict__ g,
    const float* __restrict__ be,
    const unsigned short* __restrict__ WcT, const float* __restrict__ bc,
    const float* __restrict__ wqbk, const float* __restrict__ cbk,
    unsigned short* __restrict__ qp, float* __restrict__ dotbias,
    float* __restrict__ attn_sum){
  __shared__ __align__(16) unsigned short sn[16][264];
  int b = blockIdx.x, t = threadIdx.x;
  if (t < 8) attn_sum[b*8+t] = 0.f;
  if (t < 8) dotbias[b*16+8+t] = 0.f;
  int r = t>>5, j = t&31;
  const float* pr = sf + (b*8+r)*256 + j*8;
  float v[8]; float s=0.f;
  #pragma unroll
  for (int i=0;i<8;i++){ v[i]=pr[i]; s+=v[i]; }
  s += __shfl_xor(s,1); s+=__shfl_xor(s,2); s+=__shfl_xor(s,4);
  s += __shfl_xor(s,8); s+=__shfl_xor(s,16);
  float m = s*(1.f/256.f);
  float vs=0.f;
  #pragma unroll
  for (int i=0;i<8;i++){ float d = v[i]-m; vs += d*d; }
  vs += __shfl_xor(vs,1); vs+=__shfl_xor(vs,2); vs+=__shfl_xor(vs,4);
  vs += __shfl_xor(vs,8); vs+=__shfl_xor(vs,16);
  float rstd = rsqrtf(vs*(1.f/256.f) + 1e-5f);
  float dp = 0.f;
  #pragma unroll
  for (int i=0;i<8;i++){
    int d = j*8+i;
    float snv = (v[i]-m)*rstd*g[d] + be[d];
    sn[r][d] = f2b(snv);
    dp += snv * wqbk[d];
  }
  dp += __shfl_xor(dp,1); dp+=__shfl_xor(dp,2); dp+=__shfl_xor(dp,4);
  dp += __shfl_xor(dp,8); dp+=__shfl_xor(dp,16);
  if (j==0) dotbias[b*16+r] = dp + cbk[0];
  for (int rr=8; rr<16; ++rr){ sn[rr][t]=0; if (t<8) sn[rr][256+t]=0; }
  __syncthreads();
  int lane = t&63, wv = t>>6, l16 = lane&15, quad = lane>>4;
  #pragma unroll
  for (int nt=0; nt<4; ++nt){
    int col = (wv*4+nt)*16 + l16;
    f32x4 acc = {0.f,0.f,0.f,0.f};
    #pragma unroll
    for (int kk=0;kk<8;kk++){
      int kd = kk*32 + quad*8;
      bf16x8 a = *(const bf16x8*)&sn[l16][kd];
      bf16x8 bb = *(const bf16x8*)(WcT + col*256 + kd);
      acc = mfma16(a,bb,acc);
    }
    float bcv = bc[col];
    #pragma unroll
    for (int ri=0;ri<4;ri++){
      int rw = quad*4+ri;
      qp[(b*16+rw)*256 + col] = f2b(acc[ri] + bcv);
    }
  }
}

// ---------- I2 fused: per (b, 512-token chunk): 8 sub-tiles of 64 tokens:
//   LN(x)->LDS bf16 (iter0: also write bf16 cache; iters 1,2: read cache);
//   dots via MFMA; softmax over K; accumulate partial u; attn sums ----------
__global__ __launch_bounds__(256) void k_iter(
    const float* __restrict__ in, const float* __restrict__ g,
    const float* __restrict__ be, const unsigned short* __restrict__ qp,
    const float* __restrict__ dotbias, float* __restrict__ attn_sum,
    float* __restrict__ upart, float* __restrict__ attn_out,
    const unsigned short* __restrict__ xc_r, unsigned short* __restrict__ xc_w){
  __shared__ __align__(16) unsigned short xt[64][264];
  __shared__ __align__(16) float al[64][8];
  __shared__ float bsum[8];
  int t = threadIdx.x;
  int b = blockIdx.x >> 3, sp = blockIdx.x & 7;
  if (t<8) bsum[t]=0.f;
  int lane=t&63, wv=t>>6, l16=lane&15, quad=lane>>4;
  // hoist q' fragments (constant across tiles)
  bf16x8 aq[8];
  #pragma unroll
  for (int kk=0;kk<8;kk++)
    aq[kk] = *(const bf16x8*)(qp + ((size_t)(b*16+l16))*256 + kk*32+quad*8);
  float db[4];
  #pragma unroll
  for (int ri=0;ri<4;ri++) db[ri] = dotbias[b*16 + quad*4 + ri];
  float acc8[8] = {0.f,0.f,0.f,0.f,0.f,0.f,0.f,0.f};
  int rl = t>>3, j = t&7;
  for (int tile=0; tile<8; ++tile){
    int n0 = sp*512 + tile*64;
    __syncthreads();   // protect xt/al from previous tile's readers
    // --- stage 1: tile into LDS (bf16) ---
    if (xc_r){
      #pragma unroll
      for (int p=0;p<2;p++){
        int row = p*32 + rl;
        const unsigned short* pr = xc_r + ((size_t)(b*4096 + n0 + row))*256 + j*32;
        #pragma unroll
        for (int c=0;c<4;c++)
          *(uint4*)&xt[row][j*32 + c*8] = *(const uint4*)(pr + c*8);
      }
    } else {
      #pragma unroll
      for (int p=0;p<2;p++){
        int row = p*32 + rl;
        const float* pr = in + ((size_t)(b*4096 + n0 + row))*256 + j*32;
        float v[32]; float s=0.f;
        #pragma unroll
        for (int c=0;c<8;c++) *(float4*)(v+c*4) = *(const float4*)(pr + c*4);
        #pragma unroll
        for (int i=0;i<32;i++) s += v[i];
        s += __shfl_xor(s,1); s+=__shfl_xor(s,2); s+=__shfl_xor(s,4);
        float m = s*(1.f/256.f);
        float vs=0.f;
        #pragma unroll
        for (int i=0;i<32;i++){ float d=v[i]-m; vs+=d*d; }
        vs+=__shfl_xor(vs,1); vs+=__shfl_xor(vs,2); vs+=__shfl_xor(vs,4);
        float rstd = rsqrtf(vs*(1.f/256.f)+1e-5f);
        #pragma unroll
        for (int c=0;c<4;c++){
          float o[8];
          #pragma unroll
          for (int q=0;q<8;q++){
            int d = j*32 + c*8 + q;
            o[q] = (v[c*8+q]-m)*rstd*g[d] + be[d];
          }
          uint4 w4;
          w4.x=pck(o[0],o[1]); w4.y=pck(o[2],o[3]);
          w4.z=pck(o[4],o[5]); w4.w=pck(o[6],o[7]);
          *(uint4*)&xt[row][j*32 + c*8] = w4;
          if (xc_w)
            *(uint4*)(xc_w + ((size_t)(b*4096 + n0 + row))*256 + j*32 + c*8) = w4;
        }
      }
    }
    __syncthreads();
    // --- stage 2: dots + softmax over slots ---
    f32x4 acc = {0.f,0.f,0.f,0.f};
    #pragma unroll
    for (int kk=0;kk<8;kk++){
      int kd = kk*32 + quad*8;
      bf16x8 bb = *(const bf16x8*)&xt[wv*16 + l16][kd];
      acc = mfma16(aq[kk],bb,acc);
    }
    const float scale = 0.0625f;
    float val[4];
    #pragma unroll
    for (int ri=0;ri<4;ri++) val[ri] = (acc[ri] + db[ri]) * scale;
    float mx = fmaxf(fmaxf(val[0],val[1]), fmaxf(val[2],val[3]));
    mx = fmaxf(mx, __shfl_xor(mx,16));
    float e[4], s4=0.f;
    #pragma unroll
    for (int ri=0;ri<4;ri++){ e[ri] = expf(val[ri]-mx); s4 += e[ri]; }
    float s8 = s4 + __shfl_xor(s4,16);
    float inv = 1.f/s8;
    if (quad < 2){
      int nl = wv*16 + l16;
      #pragma unroll
      for (int ri=0;ri<4;ri++){
        float av = e[ri]*inv;
        int kr = quad*4+ri;
        al[nl][kr] = av;
        if (attn_out)
          attn_out[((size_t)(b*8+kr))*4096 + n0 + nl] = av;
        float ss = av;
        ss += __shfl_xor(ss,1); ss+=__shfl_xor(ss,2);
        ss += __shfl_xor(ss,4); ss+=__shfl_xor(ss,8);
        if (l16==0) atomicAdd(&bsum[kr], ss);
      }
    }
    __syncthreads();
    // --- stage 3: accumulate u[k][c] += attn[k][n]*x[n][c] ---
    int c = t;
    for (int n=0;n<64;++n){
      float xv = b2f(xt[n][c]);
      float4 a0 = *(const float4*)&al[n][0];
      float4 a1 = *(const float4*)&al[n][4];
      acc8[0]+=a0.x*xv; acc8[1]+=a0.y*xv; acc8[2]+=a0.z*xv; acc8[3]+=a0.w*xv;
      acc8[4]+=a1.x*xv; acc8[5]+=a1.y*xv; acc8[6]+=a1.z*xv; acc8[7]+=a1.w*xv;
    }
  }
  float* o = upart + (size_t)sp*131072 + ((size_t)b*8)*256 + t;
  #pragma unroll
  for (int k2=0;k2<8;k2++) o[(size_t)k2*256] = acc8[k2];
  if (t<8) atomicAdd(&attn_sum[b*8+t], bsum[t]);
}

// ---------- I3 fused slot chain: ured + gates + GRU + LN + ffn1 + ffn2
//            (+ next-iteration slot LN + q' unless last) ----------
// grid 32 blocks, each handles 2 batches = 16 slot rows.
__global__ __launch_bounds__(256) void k_step(
    const float* __restrict__ upart, float* __restrict__ asum,
    float* __restrict__ sf, unsigned short* __restrict__ sb,
    const unsigned short* __restrict__ WvihT, const float* __restrict__ bvih,
    const unsigned short* __restrict__ Whhb, const float* __restrict__ bhh,
    const float* __restrict__ lnffg, const float* __restrict__ lnffb,
    const unsigned short* __restrict__ W1b, const float* __restrict__ b1,
    const unsigned short* __restrict__ W2b, const float* __restrict__ b2v,
    const float* __restrict__ lnsg, const float* __restrict__ lnsb,
    const unsigned short* __restrict__ WcT, const float* __restrict__ bc,
    const float* __restrict__ wqbk, const float* __restrict__ cbk,
    unsigned short* __restrict__ qp, float* __restrict__ dotb,
    float* __restrict__ out_slots, int last){
  __shared__ __align__(16) unsigned short ub16[16][264];
  __shared__ __align__(16) float hls[16][268];
  __shared__ __align__(16) unsigned short sn[16][264];
  __shared__ __align__(16) unsigned short s1t[16][520];
  __shared__ float redh[4][16], redq[4][16], mr[16], rs[16];
  int t = threadIdx.x;
  int Bk = blockIdx.x;                 // batches 2*Bk, 2*Bk+1
  int bb0 = Bk*2;
  int lane=t&63, wv=t>>6, l16=lane&15, quad=lane>>4;
  // --- stage A: reduce upart, normalize, to LDS bf16 ---
  {
    int r16 = t>>4, c0 = (t&15)*16;
    size_t base = ((size_t)(Bk*16 + r16))*256 + c0;
    float4 a0={0,0,0,0}, a1={0,0,0,0}, a2={0,0,0,0}, a3={0,0,0,0};
    #pragma unroll
    for (int sp2=0; sp2<8; ++sp2){
      const float* p = upart + (size_t)sp2*131072 + base;
      float4 u0=*(const float4*)(p+0), u1=*(const float4*)(p+4),
             u2=*(const float4*)(p+8), u3=*(const float4*)(p+12);
      a0.x+=u0.x;a0.y+=u0.y;a0.z+=u0.z;a0.w+=u0.w;
      a1.x+=u1.x;a1.y+=u1.y;a1.z+=u1.z;a1.w+=u1.w;
      a2.x+=u2.x;a2.y+=u2.y;a2.z+=u2.z;a2.w+=u2.w;
      a3.x+=u3.x;a3.y+=u3.y;a3.z+=u3.z;a3.w+=u3.w;
    }
    float inv = 1.f/(asum[Bk*16 + r16] + 1e-8f);
    float uu[16] = {a0.x,a0.y,a0.z,a0.w,a1.x,a1.y,a1.z,a1.w,
                    a2.x,a2.y,a2.z,a2.w,a3.x,a3.y,a3.z,a3.w};
    #pragma unroll
    for (int c=0;c<16;c+=2){
      *(unsigned int*)&ub16[r16][c0+c] = pck(uu[c]*inv, uu[c+1]*inv);
    }
  }
  __syncthreads();
  if (t < 16) asum[Bk*16 + t] = 0.f;   // reset for next iteration's atomics
  // --- stage B: gates via MFMA (fragment-resident) + GRU elementwise ---
  bf16x8 afi[8], afh[8];
  #pragma unroll
  for (int kk=0;kk<8;kk++){
    int kd = kk*32+quad*8;
    afi[kk] = *(const bf16x8*)&ub16[l16][kd];
    afh[kk] = *(const bf16x8*)(sb + ((size_t)(Bk*16+l16))*256 + kd);
  }
  float sh[4]={0,0,0,0}, sq[4]={0,0,0,0};
  #pragma unroll
  for (int jj=0;jj<4;jj++){
    int jt = wv*4 + jj;
    int dR = jt*16 + l16;
    f32x4 cIR={0,0,0,0}, cIZ={0,0,0,0}, cIN={0,0,0,0};
    f32x4 cHR={0,0,0,0}, cHZ={0,0,0,0}, cHN={0,0,0,0};
    #pragma unroll
    for (int kk=0;kk<8;kk++){
      int kd = kk*32+quad*8;
      cIR = mfma16(afi[kk], *(const bf16x8*)(WvihT + (size_t)dR*256 + kd), cIR);
      cIZ = mfma16(afi[kk], *(const bf16x8*)(WvihT + (size_t)(256+dR)*256 + kd), cIZ);
      cIN = mfma16(afi[kk], *(const bf16x8*)(WvihT + (size_t)(512+dR)*256 + kd), cIN);
      cHR = mfma16(afh[kk], *(const bf16x8*)(Whhb + (size_t)dR*256 + kd), cHR);
      cHZ = mfma16(afh[kk], *(const bf16x8*)(Whhb + (size_t)(256+dR)*256 + kd), cHZ);
      cHN = mfma16(afh[kk], *(const bf16x8*)(Whhb + (size_t)(512+dR)*256 + kd), cHN);
    }
    float biR = bvih[dR], biZ = bvih[256+dR], biN = bvih[512+dR];
    float bhR = bhh[dR], bhZ = bhh[256+dR], bhN = bhh[512+dR];
    #pragma unroll
    for (int ri=0;ri<4;ri++){
      int row = quad*4+ri;
      float hp = sf[((size_t)(Bk*16+row))*256 + dR];
      float rg = sigm(cIR[ri]+biR + cHR[ri]+bhR);
      float z  = sigm(cIZ[ri]+biZ + cHZ[ri]+bhZ);
      float nn = tanhf(cIN[ri]+biN + rg*(cHN[ri]+bhN));
      float h = (1.f-z)*nn + z*hp;
      hls[row][dR] = h;
      sh[ri] += h; sq[ri] += h*h;
    }
  }
  #pragma unroll
  for (int ri=0;ri<4;ri++){
    sh[ri]+=__shfl_xor(sh[ri],1); sh[ri]+=__shfl_xor(sh[ri],2);
    sh[ri]+=__shfl_xor(sh[ri],4); sh[ri]+=__shfl_xor(sh[ri],8);
    sq[ri]+=__shfl_xor(sq[ri],1); sq[ri]+=__shfl_xor(sq[ri],2);
    sq[ri]+=__shfl_xor(sq[ri],4); sq[ri]+=__shfl_xor(sq[ri],8);
  }
  if (l16==0){
    #pragma unroll
    for (int ri=0;ri<4;ri++){
      redh[wv][quad*4+ri] = sh[ri];
      redq[wv][quad*4+ri] = sq[ri];
    }
  }
  __syncthreads();
  if (t < 16){
    float s = redh[0][t]+redh[1][t]+redh[2][t]+redh[3][t];
    float q = redq[0][t]+redq[1][t]+redq[2][t]+redq[3][t];
    float m = s*(1.f/256.f);
    float var = q*(1.f/256.f) - m*m;
    mr[t] = m; rs[t] = rsqrtf(var + 1e-5f);
  }
  __syncthreads();
  // --- stage C: ff = LN(h) (bf16 into sn) ---
  {
    int row = t>>4, c0 = (t&15)*16;
    float m = mr[row], rstd = rs[row];
    #pragma unroll
    for (int c=0;c<16;c+=2){
      int d = c0+c;
      float o0 = (hls[row][d]-m)*rstd*lnffg[d] + lnffb[d];
      float o1 = (hls[row][d+1]-m)*rstd*lnffg[d+1] + lnffb[d+1];
      *(unsigned int*)&sn[row][d] = pck(o0,o1);
    }
  }
  __syncthreads();
  // --- stage D: s1 = relu(ff@W1^T + b1) ---
  {
    bf16x8 af[8];
    #pragma unroll
    for (int kk=0;kk<8;kk++)
      af[kk] = *(const bf16x8*)&sn[l16][kk*32+quad*8];
    #pragma unroll
    for (int ct=wv*8; ct<wv*8+8; ++ct){
      int col = ct*16+l16;
      f32x4 acc={0,0,0,0};
      #pragma unroll
      for (int kk=0;kk<8;kk++)
        acc = mfma16(af[kk], *(const bf16x8*)(W1b + (size_t)col*256 + kk*32+quad*8), acc);
      float bb = b1[col];
      #pragma unroll
      for (int ri=0;ri<4;ri++){
        float v2 = acc[ri]+bb; v2 = v2>0.f? v2:0.f;
        s1t[quad*4+ri][col] = f2b(v2);
      }
    }
  }
  __syncthreads();
  // --- stage E: slots = h + s1@W2^T + b2 ---
  {
    bf16x8 af[16];
    #pragma unroll
    for (int kk=0;kk<16;kk++)
      af[kk] = *(const bf16x8*)&s1t[l16][kk*32+quad*8];
    #pragma unroll
    for (int ct=wv*4; ct<wv*4+4; ++ct){
      int col = ct*16+l16;
      f32x4 acc={0,0,0,0};
      #pragma unroll
      for (int kk=0;kk<16;kk++)
        acc = mfma16(af[kk], *(const bf16x8*)(W2b + (size_t)col*512 + kk*32+quad*8), acc);
      float bb = b2v[col];
      #pragma unroll
      for (int ri=0;ri<4;ri++){
        int row = quad*4+ri;
        float v2 = acc[ri] + bb + hls[row][col];
        size_t gidx = ((size_t)(Bk*16+row))*256 + col;
        sf[gidx] = v2;
        sb[gidx] = f2b(v2);
        if (last) out_slots[gidx] = v2;
        hls[row][col] = v2;   // new slots for stage F
      }
    }
  }
  if (!last){
    __syncthreads();
    // --- stage F: LN(new slots) + dotbias + q' for next iteration ---
    {
      int row = t>>4, c0 = (t&15)*16;
      float ps=0.f, pq=0.f;
      float hv[16];
      #pragma unroll
      for (int c=0;c<16;c++){ hv[c]=hls[row][c0+c]; ps+=hv[c]; pq+=hv[c]*hv[c]; }
      ps+=__shfl_xor(ps,1); ps+=__shfl_xor(ps,2); ps+=__shfl_xor(ps,4); ps+=__shfl_xor(ps,8);
      pq+=__shfl_xor(pq,1); pq+=__shfl_xor(pq,2); pq+=__shfl_xor(pq,4); pq+=__shfl_xor(pq,8);
      float m = ps*(1.f/256.f);
      float var = pq*(1.f/256.f) - m*m;
      float rstd = rsqrtf(var + 1e-5f);
      float dp = 0.f;
      #pragma unroll
      for (int c=0;c<16;c+=2){
        int d = c0+c;
        float o0 = (hv[c]-m)*rstd*lnsg[d] + lnsb[d];
        float o1 = (hv[c+1]-m)*rstd*lnsg[d+1] + lnsb[d+1];
        dp += o0*wqbk[d] + o1*wqbk[d+1];
        *(unsigned int*)&sn[row][d] = pck(o0,o1);
      }
      dp+=__shfl_xor(dp,1); dp+=__shfl_xor(dp,2); dp+=__shfl_xor(dp,4); dp+=__shfl_xor(dp,8);
      if ((t&15)==0){
        int bloc = row>>3, rr = row&7;
        dotb[(bb0+bloc)*16 + rr] = dp + cbk[0];
      }
    }
    __syncthreads();
    {
      bf16x8 af[8];
      #pragma unroll
      for (int kk=0;kk<8;kk++)
        af[kk] = *(const bf16x8*)&sn[l16][kk*32+quad*8];
      #pragma unroll
      for (int ct=wv*4; ct<wv*4+4; ++ct){
        int col = ct*16+l16;
        f32x4 acc={0,0,0,0};
        #pragma unroll
        for (int kk=0;kk<8;kk++)
          acc = mfma16(af[kk], *(const bf16x8*)(WcT + (size_t)col*256 + kk*32+quad*8), acc);
        float bcv = bc[col];
        #pragma unroll
        for (int ri=0;ri<4;ri++){
          int row = quad*4+ri;
          int bloc = row>>3, rr = row&7;
          qp[((size_t)((bb0+bloc)*16 + rr))*256 + col] = f2b(acc[ri] + bcv);
        }
      }
    }
  }
}

// ---------- launch ----------
extern "C" void kernel_launch(void* const* d_in, const int* in_sizes, int n_in,
                              void* d_out, int out_size, void* d_ws, size_t ws_size,
                              hipStream_t stream){
  const float* inputs  = (const float*)d_in[0];
  const float* noise   = (const float*)d_in[1];
  const float* slot_mu = (const float*)d_in[2];
  const float* slot_ls = (const float*)d_in[3];
  const float* Wq   = (const float*)d_in[4];
  const float* bq   = (const float*)d_in[5];
  const float* Wk   = (const float*)d_in[6];
  const float* bk   = (const float*)d_in[7];
  const float* Wv   = (const float*)d_in[8];
  const float* bv   = (const float*)d_in[9];
  const float* W_ih = (const float*)d_in[10];
  const float* b_ih = (const float*)d_in[11];
  const float* W_hh = (const float*)d_in[12];
  const float* b_hh = (const float*)d_in[13];
  const float* ln_in_g = (const float*)d_in[14];
  const float* ln_in_b = (const float*)d_in[15];
  const float* ln_s_g  = (const float*)d_in[16];
  const float* ln_s_b  = (const float*)d_in[17];
  const float* ln_ff_g = (const float*)d_in[18];
  const float* ln_ff_b = (const float*)d_in[19];
  const float* W1 = (const float*)d_in[20];
  const float* b1 = (const float*)d_in[21];
  const float* W2 = (const float*)d_in[22];
  const float* b2 = (const float*)d_in[23];

  char* w = (char*)d_ws;
  auto alloc = [&](size_t n)->char*{ char* p=w; w += (n+255)&~(size_t)255; return p; };
  unsigned short* xc   = (unsigned short*)alloc(134217728);  // [B*N,256] bf16 LN'd cache
  float* upart         = (float*)alloc(4194304);             // [8,B,8,256] f32
  unsigned short* qp   = (unsigned short*)alloc(524288);     // [B,16,256] bf16
  float* sf            = (float*)alloc(524288);              // slots f32
  unsigned short* sb   = (unsigned short*)alloc(262144);     // slots bf16
  unsigned short* WcT  = (unsigned short*)alloc(131072);     // [256,256] bf16
  unsigned short* WvihT= (unsigned short*)alloc(393216);     // [768,256] bf16
  unsigned short* Whhb = (unsigned short*)alloc(393216);     // [768,256] bf16
  unsigned short* W1b  = (unsigned short*)alloc(262144);     // [512,256] bf16
  unsigned short* W2b  = (unsigned short*)alloc(262144);     // [256,512] bf16
  float* bc    = (float*)alloc(1024);
  float* wqbk  = (float*)alloc(1024);
  float* cbk   = (float*)alloc(256);
  float* bvih  = (float*)alloc(3072);
  float* dotb  = (float*)alloc(4096);
  float* asum  = (float*)alloc(2048);

  float* out_slots = (float*)d_out;
  float* out_attn  = out_slots + 131072;

  k_slots_init<<<dim3(512),dim3(256),0,stream>>>(noise, slot_mu, slot_ls, sf, sb);
  k_pre1<<<dim3(256),dim3(256),0,stream>>>(Wq, Wk, bq, bk, WcT, bc, wqbk, cbk);
  k_pre2<<<dim3(768),dim3(256),0,stream>>>(W_ih, Wv, bv, b_ih, WvihT, bvih);
  k_prep_b16<<<dim3(1792),dim3(256),0,stream>>>(W_hh, W1, W2, Whhb, W1b, W2b);
  k_slot_q<<<dim3(64),dim3(256),0,stream>>>(sf, ln_s_g, ln_s_b, WcT, bc, wqbk, cbk,
                                            qp, dotb, asum);

  for (int it=0; it<3; ++it){
    int last = (it==2);
    k_iter<<<dim3(512),dim3(256),0,stream>>>(
        inputs, ln_in_g, ln_in_b, qp, dotb, asum, upart,
        last ? out_attn : (float*)nullptr,
        it ? xc : (const unsigned short*)nullptr,
        it==0 ? xc : (unsigned short*)nullptr);
    k_step<<<dim3(32),dim3(256),0,stream>>>(
        upart, asum, sf, sb, WvihT, bvih, Whhb, b_hh,
        ln_ff_g, ln_ff_b, W1b, b1, W2b, b2,
        ln_s_g, ln_s_b, WcT, bc, wqbk, cbk,
        qp, dotb, last ? out_slots : (float*)nullptr, last);
  }
}